// Round 13
// baseline (56.240 us; speedup 1.0000x reference)
//
#include <hip/hip_runtime.h>

// out[b,s,:] = W[:, text[b,s]] + bias + pe[s,:]
// text: int32 [B,S]; W: f32 [D, VOCAB]; bias: f32 [D]; pe: f32 [MAX_LEN, D]
//
// Round 13: SINGLE-KERNEL. No binning pass at all: each block owns a
// (64-vocab x 64-d) W tile (staged coalesced into LDS, r7-exact); each wave
// then scans a quarter of text (32 coalesced 64-lane loads from L2-resident
// 32KB text) and processes matching tokens via __ballot + shfl broadcast.
// Kills the serial bin_k prefix (~3-4us on 1 CU) + the 2nd dispatch gap.
// r10 lesson: no nontemporal (W must stay L3-resident).
// r11 lesson: no multi-dispatch chains (launch gaps dominate).

#define VOCAB  32000
#define DMODEL 1024
#define S_LEN  2048
#define B_N    4
#define NTOK   (B_N * S_LEN)     // 8192
#define VT     64                // vocab entries per tile
#define DT     64                // d rows per tile
#define NBIN   (VOCAB / VT)      // 500
#define NDT    (DMODEL / DT)     // 16
#define NBLK   (NBIN * NDT)      // 8000
#define LSTRIDE (VT + 1)         // 65: process reads (lane+tokl)%32 -> 2-way, free

__global__ __launch_bounds__(256, 8) void embed_k(const int* __restrict__ text,
                                                  const float* __restrict__ W,
                                                  const float* __restrict__ bias,
                                                  const float* __restrict__ pe,
                                                  float* __restrict__ out) {
    __shared__ float lds[DT * LSTRIDE];      // 16.6 KB -> 8 blocks/CU

    const int bid = blockIdx.x;
    const int vt = bid >> 4;                 // 0..499
    const int dt = bid & (NDT - 1);          // 0..15
    const int v0 = vt * VT;
    const int d0 = dt * DT;
    const int t  = threadIdx.x;

    // stage W[d0:d0+64][v0:v0+64] into LDS, coalesced float4 reads (r7 exact)
    {
        const int c4 = t & 15;               // float4 column 0..15
        const int r0 = t >> 4;               // row 0..15
        #pragma unroll
        for (int i = 0; i < 4; ++i) {
            const int row = r0 + i * 16;
            const float4 w4 = *reinterpret_cast<const float4*>(
                W + (size_t)(d0 + row) * VOCAB + v0 + c4 * 4);
            float* lp = lds + row * LSTRIDE + c4 * 4;
            lp[0] = w4.x; lp[1] = w4.y; lp[2] = w4.z; lp[3] = w4.w;
        }
    }
    __syncthreads();

    const int lane = t & 63;
    const int wv   = t >> 6;                 // wave 0..3: owns text quarter
    const float bv = bias[d0 + lane];

    // scan this wave's text quarter; ballot -> process matches cooperatively
    const int qbase = wv * (NTOK / 4);       // 2048 positions per wave
    #pragma unroll 4
    for (int it = 0; it < (NTOK / 4) / 64; ++it) {   // 32 coalesced wave-loads
        const int base = qbase + it * 64;
        const int tok  = text[base + lane];
        const unsigned tokl_u = (unsigned)(tok - v0);
        unsigned long long m = __ballot(tokl_u < (unsigned)VT);
        while (m) {
            const int src = __ffsll((unsigned long long)m) - 1;
            m &= m - 1;
            const int stok = __shfl(tok, src, 64);   // wave-uniform token
            const int bs   = base + src;
            const int s    = bs & (S_LEN - 1);
            const float wval = lds[lane * LSTRIDE + (stok - v0)]; // 2-way, free
            const float pv = pe[(size_t)s * DMODEL + d0 + lane];  // 256B coalesced
            out[(size_t)bs * DMODEL + d0 + lane] = wval + bv + pv;
        }
    }
}

extern "C" void kernel_launch(void* const* d_in, const int* in_sizes, int n_in,
                              void* d_out, int out_size, void* d_ws, size_t ws_size,
                              hipStream_t stream) {
    const int*   text = (const int*)d_in[0];
    const float* W    = (const float*)d_in[1];
    const float* bias = (const float*)d_in[2];
    const float* pe   = (const float*)d_in[3];
    float*       out  = (float*)d_out;

    embed_k<<<NBLK, 256, 0, stream>>>(text, W, bias, pe, out);
}